// Round 8
// baseline (489.771 us; speedup 1.0000x reference)
//
#include <hip/hip_runtime.h>
#include <math.h>

// GCN 2-layer. Deterministic 2-level radix sort of edges by target node
// (group×bucket histogram -> scan -> disjoint-region scatter -> per-bucket
// fine sort), then SORT-FREE per-node gather aggregation (4 lanes/node,
// uint4 row loads, register acc). bf16 gather sources (3.2MB, L2-resident);
// W2 commuted past aggregation.
//   R7 lesson: shared global cursors -> 8x (=XCD count) partial-line HBM
//   write amplification (105MB for a 12.8MB payload). Deterministic offsets
//   give every block a private write region.
// edge_index: int32 (harness-converted; R2 crash proved 8E-byte buffer).
#define F_IN  128
#define F_HID 16
#define F_OUT 32
#define G     784         // binning groups
#define CSH   9           // coarse bucket = 512 nodes
#define CN    512
#define MAXB  256         // max coarse buckets (N <= 131072 -> 17-bit rows)

typedef unsigned int u32;

__device__ inline float bflo(u32 d) { return __uint_as_float(d << 16); }
__device__ inline float bfhi(u32 d) { return __uint_as_float(d & 0xFFFF0000u); }
__device__ inline u32 f2bf(float f) {
    u32 u = __float_as_uint(f);
    return (u + 0x7FFFu + ((u >> 16) & 1u)) >> 16;  // RNE
}
__device__ inline u32 pk2(float lo, float hi) { return f2bf(lo) | (f2bf(hi) << 16); }

// group x coarse-bucket histogram, transposed write hist_t[b*G + g]
__global__ void k_hist(const int* __restrict__ col, int E,
                       int* __restrict__ hist_t, int B) {
    __shared__ int h[MAXB];
    int t = threadIdx.x, g = blockIdx.x;
    for (int k = t; k < B; k += 256) h[k] = 0;
    __syncthreads();
    int cg = (E + G - 1) / G;
    int e0 = g * cg, e1 = min(E, e0 + cg);
    for (int e = e0 + t; e < e1; e += 256)
        atomicAdd(&h[col[e] >> CSH], 1);
    __syncthreads();
    for (int b = t; b < B; b += 256) hist_t[(size_t)b * G + g] = h[b];
}

// single-block exclusive scan of hist_t[M] -> off[M+1]
__global__ void k_scan(const int* __restrict__ hist_t, int* __restrict__ off,
                       int M, int E) {
    __shared__ int sd[1024];
    int t = threadIdx.x;
    int chunk = (M + 1023) / 1024;
    int i0 = t * chunk, i1 = min(M, i0 + chunk);
    int s = 0;
    for (int i = i0; i < i1; ++i) s += hist_t[i];
    sd[t] = s;
    __syncthreads();
    for (int o = 1; o < 1024; o <<= 1) {
        int x = (t >= o) ? sd[t - o] : 0;
        __syncthreads();
        sd[t] += x;
        __syncthreads();
    }
    int run = sd[t] - s;
    for (int i = i0; i < i1; ++i) { int v = hist_t[i]; off[i] = run; run += v; }
    if (t == 1023) off[M] = E;
}

// scatter packed edges to private (g,b) regions.  pack = (col&511)<<17 | row.
__global__ void k_fill(const int* __restrict__ row, const int* __restrict__ col,
                       int E, const int* __restrict__ off, u32* __restrict__ pairs,
                       int B) {
    __shared__ int cur[MAXB];
    int t = threadIdx.x, g = blockIdx.x;
    for (int b = t; b < B; b += 256) cur[b] = off[(size_t)b * G + g];
    __syncthreads();
    int cg = (E + G - 1) / G;
    int e0 = g * cg, e1 = min(E, e0 + cg);
    for (int e = e0 + t; e < e1; e += 256) {
        int c = col[e];
        int p = atomicAdd(&cur[c >> CSH], 1);
        pairs[p] = ((u32)(c & (CN - 1)) << 17) | (u32)row[e];
    }
}

// per coarse bucket: count per node, scan, emit nptr+dinv, scatter srcs sorted.
__global__ void __launch_bounds__(512)
k_sortfine(const u32* __restrict__ pairs, const int* __restrict__ off, int B, int E,
           int* __restrict__ nptr, float* __restrict__ dinv,
           int* __restrict__ srcs, int N) {
    __shared__ int cnt[CN];
    __shared__ int pre[CN];
    int t = threadIdx.x, b = blockIdx.x;
    cnt[t] = 0;
    __syncthreads();
    int s0 = off[(size_t)b * G];
    int s1 = (b == B - 1) ? E : off[(size_t)(b + 1) * G];
    for (int e = s0 + t; e < s1; e += 512)
        atomicAdd(&cnt[pairs[e] >> 17], 1);
    __syncthreads();
    int v = cnt[t];
    pre[t] = v;
    __syncthreads();
    for (int o = 1; o < 512; o <<= 1) {
        int x = (t >= o) ? pre[t - o] : 0;
        __syncthreads();
        pre[t] += x;
        __syncthreads();
    }
    int excl = pre[t] - v;
    int n = (b << CSH) + t;
    nptr[n] = s0 + excl;
    if (b == B - 1 && t == CN - 1) nptr[n + 1] = E;  // inclusive end sentinel
    if (n < N) dinv[n] = rsqrtf((float)v + 1.0f);
    __syncthreads();
    cnt[t] = s0 + excl;   // becomes cursor
    __syncthreads();
    for (int e = s0 + t; e < s1; e += 512) {
        u32 p = pairs[e];
        int r = atomicAdd(&cnt[p >> 17], 1);
        srcs[r] = (int)(p & 0x1FFFFu);
    }
}

// 16 nodes x 16 ch per block; float4-staged x; bf16-packed hs1 = dinv*(x@W1).
__global__ void k_gemm1(const float* __restrict__ x, const float* __restrict__ W1,
                        const float* __restrict__ dinv, u32* __restrict__ hs1b, int N) {
    __shared__ float sW[F_IN * F_HID];
    __shared__ float sX[16][F_IN + 4];
    int t = threadIdx.x;
    {
        const float4* W4 = (const float4*)W1;
        float4* sW4 = (float4*)sW;
#pragma unroll
        for (int k = t; k < F_IN * F_HID / 4; k += 256) sW4[k] = W4[k];
    }
    int node0 = blockIdx.x * 16;
    {
        const float4* x4 = (const float4*)(x + (size_t)node0 * F_IN);
#pragma unroll
        for (int k = t; k < 16 * F_IN / 4; k += 256) {
            int r = k >> 5, c4 = k & 31;
            float4 vv = (node0 + r < N) ? x4[k] : make_float4(0.f, 0.f, 0.f, 0.f);
            *(float4*)&sX[r][c4 * 4] = vv;
        }
    }
    __syncthreads();
    int il = t >> 4, j = t & 15;
    float acc = 0.f;
    const float* xr = sX[il];
#pragma unroll 8
    for (int k = 0; k < F_IN; ++k) acc += xr[k] * sW[k * F_HID + j];
    int n = node0 + il;
    float v = (n < N) ? acc * dinv[n] : 0.f;
    float other = __shfl_xor(v, 1);
    if (n < N && !(j & 1)) hs1b[(size_t)n * 8 + (j >> 1)] = pk2(v, other);
}

// row-gather accumulate: 4 lanes/node, full 32B rows, register acc[16].
__device__ inline void gather16(const u32* __restrict__ src, const int* __restrict__ srcs,
                                int e0, int e1, int l, float* a) {
    const uint4* H = (const uint4*)src;
    int e = e0 + l;
    for (; e + 4 < e1; e += 8) {
        int i0 = srcs[e], i1 = srcs[e + 4];
        uint4 d0 = H[(size_t)i0 * 2], d1 = H[(size_t)i0 * 2 + 1];
        uint4 d2 = H[(size_t)i1 * 2], d3 = H[(size_t)i1 * 2 + 1];
        a[0] += bflo(d0.x) + bflo(d2.x);  a[1] += bfhi(d0.x) + bfhi(d2.x);
        a[2] += bflo(d0.y) + bflo(d2.y);  a[3] += bfhi(d0.y) + bfhi(d2.y);
        a[4] += bflo(d0.z) + bflo(d2.z);  a[5] += bfhi(d0.z) + bfhi(d2.z);
        a[6] += bflo(d0.w) + bflo(d2.w);  a[7] += bfhi(d0.w) + bfhi(d2.w);
        a[8] += bflo(d1.x) + bflo(d3.x);  a[9] += bfhi(d1.x) + bfhi(d3.x);
        a[10]+= bflo(d1.y) + bflo(d3.y);  a[11]+= bfhi(d1.y) + bfhi(d3.y);
        a[12]+= bflo(d1.z) + bflo(d3.z);  a[13]+= bfhi(d1.z) + bfhi(d3.z);
        a[14]+= bflo(d1.w) + bflo(d3.w);  a[15]+= bfhi(d1.w) + bfhi(d3.w);
    }
    if (e < e1) {
        int i0 = srcs[e];
        uint4 d0 = H[(size_t)i0 * 2], d1 = H[(size_t)i0 * 2 + 1];
        a[0] += bflo(d0.x);  a[1] += bfhi(d0.x);
        a[2] += bflo(d0.y);  a[3] += bfhi(d0.y);
        a[4] += bflo(d0.z);  a[5] += bfhi(d0.z);
        a[6] += bflo(d0.w);  a[7] += bfhi(d0.w);
        a[8] += bflo(d1.x);  a[9] += bfhi(d1.x);
        a[10]+= bflo(d1.y);  a[11]+= bfhi(d1.y);
        a[12]+= bflo(d1.z);  a[13]+= bfhi(d1.z);
        a[14]+= bflo(d1.w);  a[15]+= bfhi(d1.w);
    }
}

// layer-1 agg: 64 nodes/block; fused self/dinv/bias/relu/pre-scale; bf16 out.
__global__ void k_agg1(const u32* __restrict__ hs1b, const int* __restrict__ srcs,
                       const int* __restrict__ nptr, const float* __restrict__ dinv,
                       const float* __restrict__ b1, u32* __restrict__ h1b, int N) {
    int t = threadIdx.x;
    int g = t >> 2, l = t & 3;
    int n = blockIdx.x * 64 + g;
    if (n >= N) return;
    float a[16];
#pragma unroll
    for (int k = 0; k < 16; ++k) a[k] = 0.f;
    gather16(hs1b, srcs, nptr[n], nptr[n + 1], l, a);
#pragma unroll
    for (int o = 1; o < 4; o <<= 1)
#pragma unroll
        for (int k = 0; k < 16; ++k) a[k] += __shfl_xor(a[k], o, 64);
    uint2 sd = ((const uint2*)hs1b)[(size_t)n * 4 + l];  // self, ch 4l..4l+3
    float dv = dinv[n];
    float4 bb = ((const float4*)b1)[l];
    float r0 = dv * (a[4 * l]     + bflo(sd.x)) + bb.x;
    float r1 = dv * (a[4 * l + 1] + bfhi(sd.x)) + bb.y;
    float r2 = dv * (a[4 * l + 2] + bflo(sd.y)) + bb.z;
    float r3 = dv * (a[4 * l + 3] + bfhi(sd.y)) + bb.w;
    r0 = fmaxf(r0, 0.f) * dv;  r1 = fmaxf(r1, 0.f) * dv;   // pre-scale next layer
    r2 = fmaxf(r2, 0.f) * dv;  r3 = fmaxf(r3, 0.f) * dv;
    ((uint2*)h1b)[(size_t)n * 4 + l] = make_uint2(pk2(r0, r1), pk2(r2, r3));
}

// layer-2 agg + fused 16x32 GEMM (W2) + bias + log_softmax.
__global__ void k_agg2_final(const u32* __restrict__ h1b, const int* __restrict__ srcs,
                             const int* __restrict__ nptr, const float* __restrict__ dinv,
                             const float* __restrict__ W2, const float* __restrict__ b2,
                             float* __restrict__ out, int N) {
    __shared__ float accS[64 * 17];
    __shared__ float sW2[F_HID * F_OUT];
    __shared__ float sb2[F_OUT];
    int t = threadIdx.x;
    for (int k = t; k < F_HID * F_OUT; k += 256) sW2[k] = W2[k];
    if (t < F_OUT) sb2[t] = b2[t];
    int g = t >> 2, l = t & 3;
    int n = blockIdx.x * 64 + g;
    float a[16];
#pragma unroll
    for (int k = 0; k < 16; ++k) a[k] = 0.f;
    if (n < N) gather16(h1b, srcs, nptr[n], nptr[n + 1], l, a);
#pragma unroll
    for (int o = 1; o < 4; o <<= 1)
#pragma unroll
        for (int k = 0; k < 16; ++k) a[k] += __shfl_xor(a[k], o, 64);
    if (n < N) {
        uint2 sd = ((const uint2*)h1b)[(size_t)n * 4 + l];
        float dv = dinv[n];
        accS[g * 17 + 4 * l]     = dv * (a[4 * l]     + bflo(sd.x));
        accS[g * 17 + 4 * l + 1] = dv * (a[4 * l + 1] + bfhi(sd.x));
        accS[g * 17 + 4 * l + 2] = dv * (a[4 * l + 2] + bflo(sd.y));
        accS[g * 17 + 4 * l + 3] = dv * (a[4 * l + 3] + bfhi(sd.y));
    }
    __syncthreads();
    int g2 = t >> 5, j = t & 31;
    for (int r = 0; r < 8; ++r) {
        int nl = r * 8 + g2;
        int n2 = blockIdx.x * 64 + nl;
        if (n2 < N) {
            float z = sb2[j];
#pragma unroll
            for (int k = 0; k < F_HID; ++k) z += accS[nl * 17 + k] * sW2[k * F_OUT + j];
            float m = z;
            for (int o = 16; o > 0; o >>= 1) m = fmaxf(m, __shfl_xor(m, o, 32));
            float ssum = __expf(z - m);
            for (int o = 16; o > 0; o >>= 1) ssum += __shfl_xor(ssum, o, 32);
            out[(size_t)n2 * F_OUT + j] = z - m - __logf(ssum);
        }
    }
}

static inline size_t alignup(size_t v) { return (v + 255) & ~(size_t)255; }

extern "C" void kernel_launch(void* const* d_in, const int* in_sizes, int n_in,
                              void* d_out, int out_size, void* d_ws, size_t ws_size,
                              hipStream_t stream) {
    const float* x  = (const float*)d_in[0];
    const int*   ei = (const int*)d_in[1];   // [2, E] int32
    const float* W1 = (const float*)d_in[2];
    const float* b1 = (const float*)d_in[3];
    const float* W2 = (const float*)d_in[4];
    const float* b2 = (const float*)d_in[5];
    float* out = (float*)d_out;

    int N = in_sizes[0] / F_IN;
    int E = in_sizes[1] / 2;
    const int* row = ei;
    const int* col = ei + E;
    int B = (N + CN - 1) >> CSH;             // 196 coarse buckets
    int M = B * G;                            // hist size

    // ws: hist_t[M] | off[M+1] | nptr[B*CN+1] | dinv[N] | pairs[E] | srcs[E]
    //   | hs1b[8N] | h1b[8N]   (~34 MB)
    char* w = (char*)d_ws;
    int*   hist_t = (int*)w;   w += alignup(sizeof(int) * (size_t)M);
    int*   off    = (int*)w;   w += alignup(sizeof(int) * ((size_t)M + 1));
    int*   nptr   = (int*)w;   w += alignup(sizeof(int) * ((size_t)B * CN + 1));
    float* dinv   = (float*)w; w += alignup(sizeof(float) * (size_t)N);
    u32*   pairs  = (u32*)w;   w += alignup(sizeof(u32) * (size_t)E);
    int*   srcs   = (int*)w;   w += alignup(sizeof(int) * (size_t)E);
    u32*   hs1b   = (u32*)w;   w += alignup(sizeof(u32) * (size_t)N * 8);
    u32*   h1b    = (u32*)w;

    k_hist<<<G, 256, 0, stream>>>(col, E, hist_t, B);
    k_scan<<<1, 1024, 0, stream>>>(hist_t, off, M, E);
    k_fill<<<G, 256, 0, stream>>>(row, col, E, off, pairs, B);
    k_sortfine<<<B, 512, 0, stream>>>(pairs, off, B, E, nptr, dinv, srcs, N);

    k_gemm1<<<(N + 15) / 16, 256, 0, stream>>>(x, W1, dinv, hs1b, N);
    k_agg1<<<(N + 63) / 64, 256, 0, stream>>>(hs1b, srcs, nptr, dinv, b1, h1b, N);
    k_agg2_final<<<(N + 63) / 64, 256, 0, stream>>>(h1b, srcs, nptr, dinv, W2, b2, out, N);
}

// Round 9
// 260.761 us; speedup vs baseline: 1.8782x; 1.8782x over previous
//
#include <hip/hip_runtime.h>
#include <math.h>

// GCN 2-layer. Deterministic 2-level radix sort of edges by target node
// (group×bucket histogram -> hierarchical scan -> disjoint-region scatter ->
// per-bucket fine sort), then sort-free per-node gather aggregation (4
// lanes/node, uint4 row loads, register acc). bf16 gather sources (3.2MB,
// L2-resident); W2 commuted past aggregation.
//   R7: shared global cursors -> 8x XCD partial-line write amplification.
//   R8: single-block scan of 153k entries = 248us @0.16% occ -> 3-kernel scan.
// edge_index: int32 (harness-converted; R2 crash proved 8E-byte buffer).
#define F_IN  128
#define F_HID 16
#define F_OUT 32
#define G     784         // binning groups
#define CSH   9           // coarse bucket = 512 nodes
#define CN    512
#define MAXB  256         // max coarse buckets (N <= 131072 -> 17-bit rows)
#define SCH   4096        // scan elems per block (256 thr x 16)

typedef unsigned int u32;

__device__ inline float bflo(u32 d) { return __uint_as_float(d << 16); }
__device__ inline float bfhi(u32 d) { return __uint_as_float(d & 0xFFFF0000u); }
__device__ inline u32 f2bf(float f) {
    u32 u = __float_as_uint(f);
    return (u + 0x7FFFu + ((u >> 16) & 1u)) >> 16;  // RNE
}
__device__ inline u32 pk2(float lo, float hi) { return f2bf(lo) | (f2bf(hi) << 16); }

// group x coarse-bucket histogram, transposed write hist_t[b*G + g]
__global__ void k_hist(const int* __restrict__ col, int E,
                       int* __restrict__ hist_t, int B) {
    __shared__ int h[MAXB];
    int t = threadIdx.x, g = blockIdx.x;
    for (int k = t; k < B; k += 256) h[k] = 0;
    __syncthreads();
    int cg = (E + G - 1) / G;
    int e0 = g * cg, e1 = min(E, e0 + cg);
    for (int e = e0 + t; e < e1; e += 256)
        atomicAdd(&h[col[e] >> CSH], 1);
    __syncthreads();
    for (int b = t; b < B; b += 256) hist_t[(size_t)b * G + g] = h[b];
}

// hierarchical exclusive scan of hist_t[M] -> off[M+1]  (3 kernels)
__global__ void k_scan_part(const int* __restrict__ hist_t, int* __restrict__ psum,
                            int M) {
    __shared__ int sd[256];
    int t = threadIdx.x;
    int base = blockIdx.x * SCH + t * 16;
    int s = 0;
#pragma unroll
    for (int k = 0; k < 16; ++k) { int i = base + k; if (i < M) s += hist_t[i]; }
    sd[t] = s;
    __syncthreads();
    for (int o = 128; o > 0; o >>= 1) { if (t < o) sd[t] += sd[t + o]; __syncthreads(); }
    if (t == 0) psum[blockIdx.x] = sd[0];
}

__global__ void k_scan_top(int* __restrict__ psum, int NP) {  // NP <= 256
    __shared__ int sd[256];
    int t = threadIdx.x;
    int v = (t < NP) ? psum[t] : 0;
    sd[t] = v;
    __syncthreads();
    for (int o = 1; o < 256; o <<= 1) {
        int x = (t >= o) ? sd[t - o] : 0;
        __syncthreads();
        sd[t] += x;
        __syncthreads();
    }
    if (t < NP) psum[t] = sd[t] - v;  // exclusive
}

__global__ void k_scan_out(const int* __restrict__ hist_t, const int* __restrict__ psum,
                           int* __restrict__ off, int M) {
    __shared__ int sd[256];
    int t = threadIdx.x;
    int base = blockIdx.x * SCH + t * 16;
    int v[16], s = 0;
#pragma unroll
    for (int k = 0; k < 16; ++k) {
        v[k] = (base + k < M) ? hist_t[base + k] : 0;
        s += v[k];
    }
    sd[t] = s;
    __syncthreads();
    for (int o = 1; o < 256; o <<= 1) {
        int x = (t >= o) ? sd[t - o] : 0;
        __syncthreads();
        sd[t] += x;
        __syncthreads();
    }
    int run = psum[blockIdx.x] + sd[t] - s;
#pragma unroll
    for (int k = 0; k < 16; ++k) {
        int i = base + k;
        if (i < M) off[i] = run;
        run += v[k];
        if (i == M - 1) off[M] = run;  // sentinel = E
    }
}

// scatter packed edges to private (g,b) regions.  pack = (col&511)<<17 | row.
__global__ void k_fill(const int* __restrict__ row, const int* __restrict__ col,
                       int E, const int* __restrict__ off, u32* __restrict__ pairs,
                       int B) {
    __shared__ int cur[MAXB];
    int t = threadIdx.x, g = blockIdx.x;
    for (int b = t; b < B; b += 256) cur[b] = off[(size_t)b * G + g];
    __syncthreads();
    int cg = (E + G - 1) / G;
    int e0 = g * cg, e1 = min(E, e0 + cg);
    for (int e = e0 + t; e < e1; e += 256) {
        int c = col[e];
        int p = atomicAdd(&cur[c >> CSH], 1);
        pairs[p] = ((u32)(c & (CN - 1)) << 17) | (u32)row[e];
    }
}

// per coarse bucket: count per node, scan, emit nptr+dinv, scatter srcs sorted.
__global__ void __launch_bounds__(512)
k_sortfine(const u32* __restrict__ pairs, const int* __restrict__ off, int B, int E,
           int* __restrict__ nptr, float* __restrict__ dinv,
           int* __restrict__ srcs, int N) {
    __shared__ int cnt[CN];
    __shared__ int pre[CN];
    int t = threadIdx.x, b = blockIdx.x;
    cnt[t] = 0;
    __syncthreads();
    int s0 = off[(size_t)b * G];
    int s1 = (b == B - 1) ? E : off[(size_t)(b + 1) * G];
    for (int e = s0 + t; e < s1; e += 512)
        atomicAdd(&cnt[pairs[e] >> 17], 1);
    __syncthreads();
    int v = cnt[t];
    pre[t] = v;
    __syncthreads();
    for (int o = 1; o < 512; o <<= 1) {
        int x = (t >= o) ? pre[t - o] : 0;
        __syncthreads();
        pre[t] += x;
        __syncthreads();
    }
    int excl = pre[t] - v;
    int n = (b << CSH) + t;
    nptr[n] = s0 + excl;
    if (b == B - 1 && t == CN - 1) nptr[n + 1] = E;  // inclusive end sentinel
    if (n < N) dinv[n] = rsqrtf((float)v + 1.0f);
    __syncthreads();
    cnt[t] = s0 + excl;   // becomes cursor
    __syncthreads();
    for (int e = s0 + t; e < s1; e += 512) {
        u32 p = pairs[e];
        int r = atomicAdd(&cnt[p >> 17], 1);
        srcs[r] = (int)(p & 0x1FFFFu);
    }
}

// 16 nodes x 16 ch per block; float4-staged x; bf16-packed hs1 = dinv*(x@W1).
__global__ void k_gemm1(const float* __restrict__ x, const float* __restrict__ W1,
                        const float* __restrict__ dinv, u32* __restrict__ hs1b, int N) {
    __shared__ float sW[F_IN * F_HID];
    __shared__ float sX[16][F_IN + 4];
    int t = threadIdx.x;
    {
        const float4* W4 = (const float4*)W1;
        float4* sW4 = (float4*)sW;
#pragma unroll
        for (int k = t; k < F_IN * F_HID / 4; k += 256) sW4[k] = W4[k];
    }
    int node0 = blockIdx.x * 16;
    {
        const float4* x4 = (const float4*)(x + (size_t)node0 * F_IN);
#pragma unroll
        for (int k = t; k < 16 * F_IN / 4; k += 256) {
            int r = k >> 5, c4 = k & 31;
            float4 vv = (node0 + r < N) ? x4[k] : make_float4(0.f, 0.f, 0.f, 0.f);
            *(float4*)&sX[r][c4 * 4] = vv;
        }
    }
    __syncthreads();
    int il = t >> 4, j = t & 15;
    float acc = 0.f;
    const float* xr = sX[il];
#pragma unroll 8
    for (int k = 0; k < F_IN; ++k) acc += xr[k] * sW[k * F_HID + j];
    int n = node0 + il;
    float v = (n < N) ? acc * dinv[n] : 0.f;
    float other = __shfl_xor(v, 1);
    if (n < N && !(j & 1)) hs1b[(size_t)n * 8 + (j >> 1)] = pk2(v, other);
}

// row-gather accumulate: 4 lanes/node, full 32B rows, register acc[16].
__device__ inline void gather16(const u32* __restrict__ src, const int* __restrict__ srcs,
                                int e0, int e1, int l, float* a) {
    const uint4* H = (const uint4*)src;
    int e = e0 + l;
    for (; e + 4 < e1; e += 8) {
        int i0 = srcs[e], i1 = srcs[e + 4];
        uint4 d0 = H[(size_t)i0 * 2], d1 = H[(size_t)i0 * 2 + 1];
        uint4 d2 = H[(size_t)i1 * 2], d3 = H[(size_t)i1 * 2 + 1];
        a[0] += bflo(d0.x) + bflo(d2.x);  a[1] += bfhi(d0.x) + bfhi(d2.x);
        a[2] += bflo(d0.y) + bflo(d2.y);  a[3] += bfhi(d0.y) + bfhi(d2.y);
        a[4] += bflo(d0.z) + bflo(d2.z);  a[5] += bfhi(d0.z) + bfhi(d2.z);
        a[6] += bflo(d0.w) + bflo(d2.w);  a[7] += bfhi(d0.w) + bfhi(d2.w);
        a[8] += bflo(d1.x) + bflo(d3.x);  a[9] += bfhi(d1.x) + bfhi(d3.x);
        a[10]+= bflo(d1.y) + bflo(d3.y);  a[11]+= bfhi(d1.y) + bfhi(d3.y);
        a[12]+= bflo(d1.z) + bflo(d3.z);  a[13]+= bfhi(d1.z) + bfhi(d3.z);
        a[14]+= bflo(d1.w) + bflo(d3.w);  a[15]+= bfhi(d1.w) + bfhi(d3.w);
    }
    if (e < e1) {
        int i0 = srcs[e];
        uint4 d0 = H[(size_t)i0 * 2], d1 = H[(size_t)i0 * 2 + 1];
        a[0] += bflo(d0.x);  a[1] += bfhi(d0.x);
        a[2] += bflo(d0.y);  a[3] += bfhi(d0.y);
        a[4] += bflo(d0.z);  a[5] += bfhi(d0.z);
        a[6] += bflo(d0.w);  a[7] += bfhi(d0.w);
        a[8] += bflo(d1.x);  a[9] += bfhi(d1.x);
        a[10]+= bflo(d1.y);  a[11]+= bfhi(d1.y);
        a[12]+= bflo(d1.z);  a[13]+= bfhi(d1.z);
        a[14]+= bflo(d1.w);  a[15]+= bfhi(d1.w);
    }
}

// layer-1 agg: 64 nodes/block; fused self/dinv/bias/relu/pre-scale; bf16 out.
__global__ void k_agg1(const u32* __restrict__ hs1b, const int* __restrict__ srcs,
                       const int* __restrict__ nptr, const float* __restrict__ dinv,
                       const float* __restrict__ b1, u32* __restrict__ h1b, int N) {
    int t = threadIdx.x;
    int g = t >> 2, l = t & 3;
    int n = blockIdx.x * 64 + g;
    if (n >= N) return;
    float a[16];
#pragma unroll
    for (int k = 0; k < 16; ++k) a[k] = 0.f;
    gather16(hs1b, srcs, nptr[n], nptr[n + 1], l, a);
#pragma unroll
    for (int o = 1; o < 4; o <<= 1)
#pragma unroll
        for (int k = 0; k < 16; ++k) a[k] += __shfl_xor(a[k], o, 64);
    uint2 sd = ((const uint2*)hs1b)[(size_t)n * 4 + l];  // self, ch 4l..4l+3
    float dv = dinv[n];
    float4 bb = ((const float4*)b1)[l];
    float r0 = dv * (a[4 * l]     + bflo(sd.x)) + bb.x;
    float r1 = dv * (a[4 * l + 1] + bfhi(sd.x)) + bb.y;
    float r2 = dv * (a[4 * l + 2] + bflo(sd.y)) + bb.z;
    float r3 = dv * (a[4 * l + 3] + bfhi(sd.y)) + bb.w;
    r0 = fmaxf(r0, 0.f) * dv;  r1 = fmaxf(r1, 0.f) * dv;   // pre-scale next layer
    r2 = fmaxf(r2, 0.f) * dv;  r3 = fmaxf(r3, 0.f) * dv;
    ((uint2*)h1b)[(size_t)n * 4 + l] = make_uint2(pk2(r0, r1), pk2(r2, r3));
}

// layer-2 agg + fused 16x32 GEMM (W2) + bias + log_softmax.
__global__ void k_agg2_final(const u32* __restrict__ h1b, const int* __restrict__ srcs,
                             const int* __restrict__ nptr, const float* __restrict__ dinv,
                             const float* __restrict__ W2, const float* __restrict__ b2,
                             float* __restrict__ out, int N) {
    __shared__ float accS[64 * 17];
    __shared__ float sW2[F_HID * F_OUT];
    __shared__ float sb2[F_OUT];
    int t = threadIdx.x;
    for (int k = t; k < F_HID * F_OUT; k += 256) sW2[k] = W2[k];
    if (t < F_OUT) sb2[t] = b2[t];
    int g = t >> 2, l = t & 3;
    int n = blockIdx.x * 64 + g;
    float a[16];
#pragma unroll
    for (int k = 0; k < 16; ++k) a[k] = 0.f;
    if (n < N) gather16(h1b, srcs, nptr[n], nptr[n + 1], l, a);
#pragma unroll
    for (int o = 1; o < 4; o <<= 1)
#pragma unroll
        for (int k = 0; k < 16; ++k) a[k] += __shfl_xor(a[k], o, 64);
    if (n < N) {
        uint2 sd = ((const uint2*)h1b)[(size_t)n * 4 + l];
        float dv = dinv[n];
        accS[g * 17 + 4 * l]     = dv * (a[4 * l]     + bflo(sd.x));
        accS[g * 17 + 4 * l + 1] = dv * (a[4 * l + 1] + bfhi(sd.x));
        accS[g * 17 + 4 * l + 2] = dv * (a[4 * l + 2] + bflo(sd.y));
        accS[g * 17 + 4 * l + 3] = dv * (a[4 * l + 3] + bfhi(sd.y));
    }
    __syncthreads();
    int g2 = t >> 5, j = t & 31;
    for (int r = 0; r < 8; ++r) {
        int nl = r * 8 + g2;
        int n2 = blockIdx.x * 64 + nl;
        if (n2 < N) {
            float z = sb2[j];
#pragma unroll
            for (int k = 0; k < F_HID; ++k) z += accS[nl * 17 + k] * sW2[k * F_OUT + j];
            float m = z;
            for (int o = 16; o > 0; o >>= 1) m = fmaxf(m, __shfl_xor(m, o, 32));
            float ssum = __expf(z - m);
            for (int o = 16; o > 0; o >>= 1) ssum += __shfl_xor(ssum, o, 32);
            out[(size_t)n2 * F_OUT + j] = z - m - __logf(ssum);
        }
    }
}

static inline size_t alignup(size_t v) { return (v + 255) & ~(size_t)255; }

extern "C" void kernel_launch(void* const* d_in, const int* in_sizes, int n_in,
                              void* d_out, int out_size, void* d_ws, size_t ws_size,
                              hipStream_t stream) {
    const float* x  = (const float*)d_in[0];
    const int*   ei = (const int*)d_in[1];   // [2, E] int32
    const float* W1 = (const float*)d_in[2];
    const float* b1 = (const float*)d_in[3];
    const float* W2 = (const float*)d_in[4];
    const float* b2 = (const float*)d_in[5];
    float* out = (float*)d_out;

    int N = in_sizes[0] / F_IN;
    int E = in_sizes[1] / 2;
    const int* row = ei;
    const int* col = ei + E;
    int B = (N + CN - 1) >> CSH;             // 196 coarse buckets
    int M = B * G;                            // hist size (153,664)
    int NP = (M + SCH - 1) / SCH;             // scan blocks (38, <=256)

    // ws: hist_t[M] | off[M+1] | psum[256] | nptr[B*CN+1] | dinv[N] |
    //     pairs[E] | srcs[E] | hs1b[8N] | h1b[8N]   (~34 MB)
    char* w = (char*)d_ws;
    int*   hist_t = (int*)w;   w += alignup(sizeof(int) * (size_t)M);
    int*   off    = (int*)w;   w += alignup(sizeof(int) * ((size_t)M + 1));
    int*   psum   = (int*)w;   w += alignup(sizeof(int) * 256);
    int*   nptr   = (int*)w;   w += alignup(sizeof(int) * ((size_t)B * CN + 1));
    float* dinv   = (float*)w; w += alignup(sizeof(float) * (size_t)N);
    u32*   pairs  = (u32*)w;   w += alignup(sizeof(u32) * (size_t)E);
    int*   srcs   = (int*)w;   w += alignup(sizeof(int) * (size_t)E);
    u32*   hs1b   = (u32*)w;   w += alignup(sizeof(u32) * (size_t)N * 8);
    u32*   h1b    = (u32*)w;

    k_hist<<<G, 256, 0, stream>>>(col, E, hist_t, B);
    k_scan_part<<<NP, 256, 0, stream>>>(hist_t, psum, M);
    k_scan_top<<<1, 256, 0, stream>>>(psum, NP);
    k_scan_out<<<NP, 256, 0, stream>>>(hist_t, psum, off, M);
    k_fill<<<G, 256, 0, stream>>>(row, col, E, off, pairs, B);
    k_sortfine<<<B, 512, 0, stream>>>(pairs, off, B, E, nptr, dinv, srcs, N);

    k_gemm1<<<(N + 15) / 16, 256, 0, stream>>>(x, W1, dinv, hs1b, N);
    k_agg1<<<(N + 63) / 64, 256, 0, stream>>>(hs1b, srcs, nptr, dinv, b1, h1b, N);
    k_agg2_final<<<(N + 63) / 64, 256, 0, stream>>>(h1b, srcs, nptr, dinv, W2, b2, out, N);
}

// Round 10
// 253.672 us; speedup vs baseline: 1.9307x; 1.0279x over previous
//
#include <hip/hip_runtime.h>
#include <math.h>

// GCN 2-layer. Deterministic 2-level radix sort of edges by target node
// (group×bucket histogram -> hierarchical scan -> disjoint-region scatter ->
// per-bucket fine sort), then sort-free per-node gather aggregation (4
// lanes/node, uint4 row loads, register acc). bf16 gather sources (3.2MB,
// L2-resident); W2 commuted past aggregation.
//   R7: shared global cursors -> 8x XCD partial-line write amplification.
//   R8: single-block 153k scan = 248us -> 3-kernel hierarchical scan.
//   R9: k_fill WRITE 4x amp from adjacent groups on different XCDs ->
//       XCD-affinity swizzle (g=(p%8)*(G/8)+p/8) + 64B regions (G=512) +
//       256-node buckets (B=391) for 2x sortfine parallelism.
// edge_index: int32 (harness-converted; R2 crash proved 8E-byte buffer).
#define F_IN  128
#define F_HID 16
#define F_OUT 32
#define G     512         // binning groups (multiple of 8 for swizzle)
#define CSH   8           // coarse bucket = 256 nodes
#define CN    256
#define MAXB  512         // max coarse buckets (N <= 131072 -> 17-bit rows)
#define SCH   4096        // scan elems per block (256 thr x 16)

typedef unsigned int u32;

__device__ inline float bflo(u32 d) { return __uint_as_float(d << 16); }
__device__ inline float bfhi(u32 d) { return __uint_as_float(d & 0xFFFF0000u); }
__device__ inline u32 f2bf(float f) {
    u32 u = __float_as_uint(f);
    return (u + 0x7FFFu + ((u >> 16) & 1u)) >> 16;  // RNE
}
__device__ inline u32 pk2(float lo, float hi) { return f2bf(lo) | (f2bf(hi) << 16); }

// group x coarse-bucket histogram, transposed write hist_t[b*G + g]
__global__ void k_hist(const int* __restrict__ col, int E,
                       int* __restrict__ hist_t, int B) {
    __shared__ int h[MAXB];
    int t = threadIdx.x;
    int p = blockIdx.x;
    int g = (p & 7) * (G / 8) + (p >> 3);   // XCD-affinity swizzle
    for (int k = t; k < B; k += 256) h[k] = 0;
    __syncthreads();
    int cg = (E + G - 1) / G;
    int e0 = g * cg, e1 = min(E, e0 + cg);
    for (int e = e0 + t; e < e1; e += 256)
        atomicAdd(&h[col[e] >> CSH], 1);
    __syncthreads();
    for (int b = t; b < B; b += 256) hist_t[(size_t)b * G + g] = h[b];
}

// hierarchical exclusive scan of hist_t[M] -> off[M+1]  (3 kernels)
__global__ void k_scan_part(const int* __restrict__ hist_t, int* __restrict__ psum,
                            int M) {
    __shared__ int sd[256];
    int t = threadIdx.x;
    int base = blockIdx.x * SCH + t * 16;
    int s = 0;
#pragma unroll
    for (int k = 0; k < 16; ++k) { int i = base + k; if (i < M) s += hist_t[i]; }
    sd[t] = s;
    __syncthreads();
    for (int o = 128; o > 0; o >>= 1) { if (t < o) sd[t] += sd[t + o]; __syncthreads(); }
    if (t == 0) psum[blockIdx.x] = sd[0];
}

__global__ void k_scan_top(int* __restrict__ psum, int NP) {  // NP <= 256
    __shared__ int sd[256];
    int t = threadIdx.x;
    int v = (t < NP) ? psum[t] : 0;
    sd[t] = v;
    __syncthreads();
    for (int o = 1; o < 256; o <<= 1) {
        int x = (t >= o) ? sd[t - o] : 0;
        __syncthreads();
        sd[t] += x;
        __syncthreads();
    }
    if (t < NP) psum[t] = sd[t] - v;  // exclusive
}

__global__ void k_scan_out(const int* __restrict__ hist_t, const int* __restrict__ psum,
                           int* __restrict__ off, int M) {
    __shared__ int sd[256];
    int t = threadIdx.x;
    int base = blockIdx.x * SCH + t * 16;
    int v[16], s = 0;
#pragma unroll
    for (int k = 0; k < 16; ++k) {
        v[k] = (base + k < M) ? hist_t[base + k] : 0;
        s += v[k];
    }
    sd[t] = s;
    __syncthreads();
    for (int o = 1; o < 256; o <<= 1) {
        int x = (t >= o) ? sd[t - o] : 0;
        __syncthreads();
        sd[t] += x;
        __syncthreads();
    }
    int run = psum[blockIdx.x] + sd[t] - s;
#pragma unroll
    for (int k = 0; k < 16; ++k) {
        int i = base + k;
        if (i < M) off[i] = run;
        run += v[k];
        if (i == M - 1) off[M] = run;  // sentinel = E
    }
}

// scatter packed edges to private (g,b) regions.  pack = (col&255)<<17 | row.
__global__ void k_fill(const int* __restrict__ row, const int* __restrict__ col,
                       int E, const int* __restrict__ off, u32* __restrict__ pairs,
                       int B) {
    __shared__ int cur[MAXB];
    int t = threadIdx.x;
    int p = blockIdx.x;
    int g = (p & 7) * (G / 8) + (p >> 3);   // XCD-affinity swizzle
    for (int b = t; b < B; b += 256) cur[b] = off[(size_t)b * G + g];
    __syncthreads();
    int cg = (E + G - 1) / G;
    int e0 = g * cg, e1 = min(E, e0 + cg);
    for (int e = e0 + t; e < e1; e += 256) {
        int c = col[e];
        int ppos = atomicAdd(&cur[c >> CSH], 1);
        pairs[ppos] = ((u32)(c & (CN - 1)) << 17) | (u32)row[e];
    }
}

// per coarse bucket: count per node, scan, emit nptr+dinv, scatter srcs sorted.
__global__ void k_sortfine(const u32* __restrict__ pairs, const int* __restrict__ off,
                           int B, int chunkB, int E,
                           int* __restrict__ nptr, float* __restrict__ dinv,
                           int* __restrict__ srcs, int N) {
    __shared__ int cnt[CN];
    __shared__ int pre[CN];
    int t = threadIdx.x;
    int p = blockIdx.x;
    int b = (p & 7) * chunkB + (p >> 3);    // XCD-affinity swizzle (padded grid)
    if (b >= B) return;
    cnt[t] = 0;
    __syncthreads();
    int s0 = off[(size_t)b * G];
    int s1 = (b == B - 1) ? E : off[(size_t)(b + 1) * G];
    for (int e = s0 + t; e < s1; e += 256)
        atomicAdd(&cnt[pairs[e] >> 17], 1);
    __syncthreads();
    int v = cnt[t];
    pre[t] = v;
    __syncthreads();
    for (int o = 1; o < 256; o <<= 1) {
        int x = (t >= o) ? pre[t - o] : 0;
        __syncthreads();
        pre[t] += x;
        __syncthreads();
    }
    int excl = pre[t] - v;
    int n = (b << CSH) + t;
    nptr[n] = s0 + excl;
    if (b == B - 1 && t == CN - 1) nptr[n + 1] = E;  // sentinel (if N==B*CN)
    if (n < N) dinv[n] = rsqrtf((float)v + 1.0f);
    __syncthreads();
    cnt[t] = s0 + excl;   // becomes cursor
    __syncthreads();
    for (int e = s0 + t; e < s1; e += 256) {
        u32 pk = pairs[e];
        int r = atomicAdd(&cnt[pk >> 17], 1);
        srcs[r] = (int)(pk & 0x1FFFFu);
    }
}

// 16 nodes x 16 ch per block; float4-staged x; bf16-packed hs1 = dinv*(x@W1).
__global__ void k_gemm1(const float* __restrict__ x, const float* __restrict__ W1,
                        const float* __restrict__ dinv, u32* __restrict__ hs1b, int N) {
    __shared__ float sW[F_IN * F_HID];
    __shared__ float sX[16][F_IN + 4];
    int t = threadIdx.x;
    {
        const float4* W4 = (const float4*)W1;
        float4* sW4 = (float4*)sW;
#pragma unroll
        for (int k = t; k < F_IN * F_HID / 4; k += 256) sW4[k] = W4[k];
    }
    int node0 = blockIdx.x * 16;
    {
        const float4* x4 = (const float4*)(x + (size_t)node0 * F_IN);
#pragma unroll
        for (int k = t; k < 16 * F_IN / 4; k += 256) {
            int r = k >> 5, c4 = k & 31;
            float4 vv = (node0 + r < N) ? x4[k] : make_float4(0.f, 0.f, 0.f, 0.f);
            *(float4*)&sX[r][c4 * 4] = vv;
        }
    }
    __syncthreads();
    int il = t >> 4, j = t & 15;
    float acc = 0.f;
    const float* xr = sX[il];
#pragma unroll 8
    for (int k = 0; k < F_IN; ++k) acc += xr[k] * sW[k * F_HID + j];
    int n = node0 + il;
    float v = (n < N) ? acc * dinv[n] : 0.f;
    float other = __shfl_xor(v, 1);
    if (n < N && !(j & 1)) hs1b[(size_t)n * 8 + (j >> 1)] = pk2(v, other);
}

// row-gather accumulate: 4 lanes/node, full 32B rows, register acc[16].
__device__ inline void gather16(const u32* __restrict__ src, const int* __restrict__ srcs,
                                int e0, int e1, int l, float* a) {
    const uint4* H = (const uint4*)src;
    int e = e0 + l;
    for (; e + 4 < e1; e += 8) {
        int i0 = srcs[e], i1 = srcs[e + 4];
        uint4 d0 = H[(size_t)i0 * 2], d1 = H[(size_t)i0 * 2 + 1];
        uint4 d2 = H[(size_t)i1 * 2], d3 = H[(size_t)i1 * 2 + 1];
        a[0] += bflo(d0.x) + bflo(d2.x);  a[1] += bfhi(d0.x) + bfhi(d2.x);
        a[2] += bflo(d0.y) + bflo(d2.y);  a[3] += bfhi(d0.y) + bfhi(d2.y);
        a[4] += bflo(d0.z) + bflo(d2.z);  a[5] += bfhi(d0.z) + bfhi(d2.z);
        a[6] += bflo(d0.w) + bflo(d2.w);  a[7] += bfhi(d0.w) + bfhi(d2.w);
        a[8] += bflo(d1.x) + bflo(d3.x);  a[9] += bfhi(d1.x) + bfhi(d3.x);
        a[10]+= bflo(d1.y) + bflo(d3.y);  a[11]+= bfhi(d1.y) + bfhi(d3.y);
        a[12]+= bflo(d1.z) + bflo(d3.z);  a[13]+= bfhi(d1.z) + bfhi(d3.z);
        a[14]+= bflo(d1.w) + bflo(d3.w);  a[15]+= bfhi(d1.w) + bfhi(d3.w);
    }
    if (e < e1) {
        int i0 = srcs[e];
        uint4 d0 = H[(size_t)i0 * 2], d1 = H[(size_t)i0 * 2 + 1];
        a[0] += bflo(d0.x);  a[1] += bfhi(d0.x);
        a[2] += bflo(d0.y);  a[3] += bfhi(d0.y);
        a[4] += bflo(d0.z);  a[5] += bfhi(d0.z);
        a[6] += bflo(d0.w);  a[7] += bfhi(d0.w);
        a[8] += bflo(d1.x);  a[9] += bfhi(d1.x);
        a[10]+= bflo(d1.y);  a[11]+= bfhi(d1.y);
        a[12]+= bflo(d1.z);  a[13]+= bfhi(d1.z);
        a[14]+= bflo(d1.w);  a[15]+= bfhi(d1.w);
    }
}

// layer-1 agg: 64 nodes/block; fused self/dinv/bias/relu/pre-scale; bf16 out.
__global__ void k_agg1(const u32* __restrict__ hs1b, const int* __restrict__ srcs,
                       const int* __restrict__ nptr, const float* __restrict__ dinv,
                       const float* __restrict__ b1, u32* __restrict__ h1b, int N) {
    int t = threadIdx.x;
    int g = t >> 2, l = t & 3;
    int n = blockIdx.x * 64 + g;
    if (n >= N) return;
    float a[16];
#pragma unroll
    for (int k = 0; k < 16; ++k) a[k] = 0.f;
    gather16(hs1b, srcs, nptr[n], nptr[n + 1], l, a);
#pragma unroll
    for (int o = 1; o < 4; o <<= 1)
#pragma unroll
        for (int k = 0; k < 16; ++k) a[k] += __shfl_xor(a[k], o, 64);
    uint2 sd = ((const uint2*)hs1b)[(size_t)n * 4 + l];  // self, ch 4l..4l+3
    float dv = dinv[n];
    float4 bb = ((const float4*)b1)[l];
    float r0 = dv * (a[4 * l]     + bflo(sd.x)) + bb.x;
    float r1 = dv * (a[4 * l + 1] + bfhi(sd.x)) + bb.y;
    float r2 = dv * (a[4 * l + 2] + bflo(sd.y)) + bb.z;
    float r3 = dv * (a[4 * l + 3] + bfhi(sd.y)) + bb.w;
    r0 = fmaxf(r0, 0.f) * dv;  r1 = fmaxf(r1, 0.f) * dv;   // pre-scale next layer
    r2 = fmaxf(r2, 0.f) * dv;  r3 = fmaxf(r3, 0.f) * dv;
    ((uint2*)h1b)[(size_t)n * 4 + l] = make_uint2(pk2(r0, r1), pk2(r2, r3));
}

// layer-2 agg + fused 16x32 GEMM (W2) + bias + log_softmax.
__global__ void k_agg2_final(const u32* __restrict__ h1b, const int* __restrict__ srcs,
                             const int* __restrict__ nptr, const float* __restrict__ dinv,
                             const float* __restrict__ W2, const float* __restrict__ b2,
                             float* __restrict__ out, int N) {
    __shared__ float accS[64 * 17];
    __shared__ float sW2[F_HID * F_OUT];
    __shared__ float sb2[F_OUT];
    int t = threadIdx.x;
    for (int k = t; k < F_HID * F_OUT; k += 256) sW2[k] = W2[k];
    if (t < F_OUT) sb2[t] = b2[t];
    int g = t >> 2, l = t & 3;
    int n = blockIdx.x * 64 + g;
    float a[16];
#pragma unroll
    for (int k = 0; k < 16; ++k) a[k] = 0.f;
    if (n < N) gather16(h1b, srcs, nptr[n], nptr[n + 1], l, a);
#pragma unroll
    for (int o = 1; o < 4; o <<= 1)
#pragma unroll
        for (int k = 0; k < 16; ++k) a[k] += __shfl_xor(a[k], o, 64);
    if (n < N) {
        uint2 sd = ((const uint2*)h1b)[(size_t)n * 4 + l];
        float dv = dinv[n];
        accS[g * 17 + 4 * l]     = dv * (a[4 * l]     + bflo(sd.x));
        accS[g * 17 + 4 * l + 1] = dv * (a[4 * l + 1] + bfhi(sd.x));
        accS[g * 17 + 4 * l + 2] = dv * (a[4 * l + 2] + bflo(sd.y));
        accS[g * 17 + 4 * l + 3] = dv * (a[4 * l + 3] + bfhi(sd.y));
    }
    __syncthreads();
    int g2 = t >> 5, j = t & 31;
    for (int r = 0; r < 8; ++r) {
        int nl = r * 8 + g2;
        int n2 = blockIdx.x * 64 + nl;
        if (n2 < N) {
            float z = sb2[j];
#pragma unroll
            for (int k = 0; k < F_HID; ++k) z += accS[nl * 17 + k] * sW2[k * F_OUT + j];
            float m = z;
            for (int o = 16; o > 0; o >>= 1) m = fmaxf(m, __shfl_xor(m, o, 32));
            float ssum = __expf(z - m);
            for (int o = 16; o > 0; o >>= 1) ssum += __shfl_xor(ssum, o, 32);
            out[(size_t)n2 * F_OUT + j] = z - m - __logf(ssum);
        }
    }
}

static inline size_t alignup(size_t v) { return (v + 255) & ~(size_t)255; }

extern "C" void kernel_launch(void* const* d_in, const int* in_sizes, int n_in,
                              void* d_out, int out_size, void* d_ws, size_t ws_size,
                              hipStream_t stream) {
    const float* x  = (const float*)d_in[0];
    const int*   ei = (const int*)d_in[1];   // [2, E] int32
    const float* W1 = (const float*)d_in[2];
    const float* b1 = (const float*)d_in[3];
    const float* W2 = (const float*)d_in[4];
    const float* b2 = (const float*)d_in[5];
    float* out = (float*)d_out;

    int N = in_sizes[0] / F_IN;
    int E = in_sizes[1] / 2;
    const int* row = ei;
    const int* col = ei + E;
    int B = (N + CN - 1) >> CSH;             // 391 coarse buckets
    int chunkB = (B + 7) >> 3;               // 49 -> padded grid 392
    int M = B * G;                            // hist size (200,192)
    int NP = (M + SCH - 1) / SCH;             // scan blocks (49, <=256)

    // ws: hist_t[M] | off[M+1] | psum[256] | nptr[B*CN+1] | dinv[N] |
    //     pairs[E] | srcs[E] | hs1b[8N] | h1b[8N]   (~35 MB)
    char* w = (char*)d_ws;
    int*   hist_t = (int*)w;   w += alignup(sizeof(int) * (size_t)M);
    int*   off    = (int*)w;   w += alignup(sizeof(int) * ((size_t)M + 1));
    int*   psum   = (int*)w;   w += alignup(sizeof(int) * 256);
    int*   nptr   = (int*)w;   w += alignup(sizeof(int) * ((size_t)B * CN + 1));
    float* dinv   = (float*)w; w += alignup(sizeof(float) * (size_t)N);
    u32*   pairs  = (u32*)w;   w += alignup(sizeof(u32) * (size_t)E);
    int*   srcs   = (int*)w;   w += alignup(sizeof(int) * (size_t)E);
    u32*   hs1b   = (u32*)w;   w += alignup(sizeof(u32) * (size_t)N * 8);
    u32*   h1b    = (u32*)w;

    k_hist<<<G, 256, 0, stream>>>(col, E, hist_t, B);
    k_scan_part<<<NP, 256, 0, stream>>>(hist_t, psum, M);
    k_scan_top<<<1, 256, 0, stream>>>(psum, NP);
    k_scan_out<<<NP, 256, 0, stream>>>(hist_t, psum, off, M);
    k_fill<<<G, 256, 0, stream>>>(row, col, E, off, pairs, B);
    k_sortfine<<<chunkB * 8, 256, 0, stream>>>(pairs, off, B, chunkB, E, nptr, dinv, srcs, N);

    k_gemm1<<<(N + 15) / 16, 256, 0, stream>>>(x, W1, dinv, hs1b, N);
    k_agg1<<<(N + 63) / 64, 256, 0, stream>>>(hs1b, srcs, nptr, dinv, b1, h1b, N);
    k_agg2_final<<<(N + 63) / 64, 256, 0, stream>>>(h1b, srcs, nptr, dinv, W2, b2, out, N);
}

// Round 11
// 246.866 us; speedup vs baseline: 1.9840x; 1.0276x over previous
//
#include <hip/hip_runtime.h>
#include <math.h>

// GCN 2-layer. Deterministic 2-level radix sort of edges by target node
// (group×bucket histogram -> hierarchical scan -> disjoint-region scatter ->
// per-bucket fine sort), then sort-free per-node gather aggregation.
// bf16 gather sources (3.2MB, L2-resident); W2 commuted past aggregation.
//   R7: shared global cursors -> 8x XCD partial-line write amplification.
//   R8: single-block 153k scan = 248us -> 3-kernel hierarchical scan.
//   R9: adjacent groups on different XCDs -> XCD-affinity swizzle, 64B regions.
//   R10: aggs are scattered-address-issue bound (41us vs 6us BW) -> lane-PAIR
//        row split: 2 lanes share one 32B row (same 64B line, coalescer
//        merges) -> half the distinct lines per vmem inst, half total lookups.
//        + sortfine stages pairs in LDS (kills 2nd 12.8MB global read).
// edge_index: int32 (harness-converted; R2 crash proved 8E-byte buffer).
#define F_IN  128
#define F_HID 16
#define F_OUT 32
#define G     512         // binning groups (multiple of 8 for swizzle)
#define CSH   8           // coarse bucket = 256 nodes
#define CN    256
#define MAXB  512         // max coarse buckets (N <= 131072 -> 17-bit rows)
#define SCH   4096        // scan elems per block (256 thr x 16)
#define CAPE  9216        // LDS-staged edges per bucket (mean 8184, sd ~90)

typedef unsigned int u32;

__device__ inline float bflo(u32 d) { return __uint_as_float(d << 16); }
__device__ inline float bfhi(u32 d) { return __uint_as_float(d & 0xFFFF0000u); }
__device__ inline u32 f2bf(float f) {
    u32 u = __float_as_uint(f);
    return (u + 0x7FFFu + ((u >> 16) & 1u)) >> 16;  // RNE
}
__device__ inline u32 pk2(float lo, float hi) { return f2bf(lo) | (f2bf(hi) << 16); }

// group x coarse-bucket histogram, transposed write hist_t[b*G + g]
__global__ void k_hist(const int* __restrict__ col, int E,
                       int* __restrict__ hist_t, int B) {
    __shared__ int h[MAXB];
    int t = threadIdx.x;
    int p = blockIdx.x;
    int g = (p & 7) * (G / 8) + (p >> 3);   // XCD-affinity swizzle
    for (int k = t; k < B; k += 256) h[k] = 0;
    __syncthreads();
    int cg = (E + G - 1) / G;
    int e0 = g * cg, e1 = min(E, e0 + cg);
    for (int e = e0 + t; e < e1; e += 256)
        atomicAdd(&h[col[e] >> CSH], 1);
    __syncthreads();
    for (int b = t; b < B; b += 256) hist_t[(size_t)b * G + g] = h[b];
}

// hierarchical exclusive scan of hist_t[M] -> off[M+1]  (3 kernels)
__global__ void k_scan_part(const int* __restrict__ hist_t, int* __restrict__ psum,
                            int M) {
    __shared__ int sd[256];
    int t = threadIdx.x;
    int base = blockIdx.x * SCH + t * 16;
    int s = 0;
#pragma unroll
    for (int k = 0; k < 16; ++k) { int i = base + k; if (i < M) s += hist_t[i]; }
    sd[t] = s;
    __syncthreads();
    for (int o = 128; o > 0; o >>= 1) { if (t < o) sd[t] += sd[t + o]; __syncthreads(); }
    if (t == 0) psum[blockIdx.x] = sd[0];
}

__global__ void k_scan_top(int* __restrict__ psum, int NP) {  // NP <= 256
    __shared__ int sd[256];
    int t = threadIdx.x;
    int v = (t < NP) ? psum[t] : 0;
    sd[t] = v;
    __syncthreads();
    for (int o = 1; o < 256; o <<= 1) {
        int x = (t >= o) ? sd[t - o] : 0;
        __syncthreads();
        sd[t] += x;
        __syncthreads();
    }
    if (t < NP) psum[t] = sd[t] - v;  // exclusive
}

__global__ void k_scan_out(const int* __restrict__ hist_t, const int* __restrict__ psum,
                           int* __restrict__ off, int M) {
    __shared__ int sd[256];
    int t = threadIdx.x;
    int base = blockIdx.x * SCH + t * 16;
    int v[16], s = 0;
#pragma unroll
    for (int k = 0; k < 16; ++k) {
        v[k] = (base + k < M) ? hist_t[base + k] : 0;
        s += v[k];
    }
    sd[t] = s;
    __syncthreads();
    for (int o = 1; o < 256; o <<= 1) {
        int x = (t >= o) ? sd[t - o] : 0;
        __syncthreads();
        sd[t] += x;
        __syncthreads();
    }
    int run = psum[blockIdx.x] + sd[t] - s;
#pragma unroll
    for (int k = 0; k < 16; ++k) {
        int i = base + k;
        if (i < M) off[i] = run;
        run += v[k];
        if (i == M - 1) off[M] = run;  // sentinel = E
    }
}

// scatter packed edges to private (g,b) regions.  pack = (col&255)<<17 | row.
__global__ void k_fill(const int* __restrict__ row, const int* __restrict__ col,
                       int E, const int* __restrict__ off, u32* __restrict__ pairs,
                       int B) {
    __shared__ int cur[MAXB];
    int t = threadIdx.x;
    int p = blockIdx.x;
    int g = (p & 7) * (G / 8) + (p >> 3);   // XCD-affinity swizzle
    for (int b = t; b < B; b += 256) cur[b] = off[(size_t)b * G + g];
    __syncthreads();
    int cg = (E + G - 1) / G;
    int e0 = g * cg, e1 = min(E, e0 + cg);
    for (int e = e0 + t; e < e1; e += 256) {
        int c = col[e];
        int ppos = atomicAdd(&cur[c >> CSH], 1);
        pairs[ppos] = ((u32)(c & (CN - 1)) << 17) | (u32)row[e];
    }
}

// per coarse bucket: count per node, scan, emit nptr+dinv, scatter srcs sorted.
// pairs staged in LDS on first pass (overflow falls back to global).
__global__ void k_sortfine(const u32* __restrict__ pairs, const int* __restrict__ off,
                           int B, int chunkB, int E,
                           int* __restrict__ nptr, float* __restrict__ dinv,
                           int* __restrict__ srcs, int N) {
    __shared__ u32 sp[CAPE];
    __shared__ int cnt[CN];
    __shared__ int pre[CN];
    int t = threadIdx.x;
    int p = blockIdx.x;
    int b = (p & 7) * chunkB + (p >> 3);    // XCD-affinity swizzle (padded grid)
    if (b >= B) return;
    cnt[t] = 0;
    __syncthreads();
    int s0 = off[(size_t)b * G];
    int s1 = (b == B - 1) ? E : off[(size_t)(b + 1) * G];
    for (int e = s0 + t; e < s1; e += 256) {
        u32 v = pairs[e];
        int li = e - s0;
        if (li < CAPE) sp[li] = v;
        atomicAdd(&cnt[v >> 17], 1);
    }
    __syncthreads();
    int v = cnt[t];
    pre[t] = v;
    __syncthreads();
    for (int o = 1; o < 256; o <<= 1) {
        int x = (t >= o) ? pre[t - o] : 0;
        __syncthreads();
        pre[t] += x;
        __syncthreads();
    }
    int excl = pre[t] - v;
    int n = (b << CSH) + t;
    nptr[n] = s0 + excl;
    if (b == B - 1 && t == CN - 1) nptr[n + 1] = E;  // sentinel
    if (n < N) dinv[n] = rsqrtf((float)v + 1.0f);
    __syncthreads();
    cnt[t] = s0 + excl;   // becomes cursor
    __syncthreads();
    for (int e = s0 + t; e < s1; e += 256) {
        int li = e - s0;
        u32 pk = (li < CAPE) ? sp[li] : pairs[e];
        int r = atomicAdd(&cnt[pk >> 17], 1);
        srcs[r] = (int)(pk & 0x1FFFFu);
    }
}

// 16 nodes x 16 ch per block; float4-staged x; bf16-packed hs1 = dinv*(x@W1).
__global__ void k_gemm1(const float* __restrict__ x, const float* __restrict__ W1,
                        const float* __restrict__ dinv, u32* __restrict__ hs1b, int N) {
    __shared__ float sW[F_IN * F_HID];
    __shared__ float sX[16][F_IN + 4];
    int t = threadIdx.x;
    {
        const float4* W4 = (const float4*)W1;
        float4* sW4 = (float4*)sW;
#pragma unroll
        for (int k = t; k < F_IN * F_HID / 4; k += 256) sW4[k] = W4[k];
    }
    int node0 = blockIdx.x * 16;
    {
        const float4* x4 = (const float4*)(x + (size_t)node0 * F_IN);
#pragma unroll
        for (int k = t; k < 16 * F_IN / 4; k += 256) {
            int r = k >> 5, c4 = k & 31;
            float4 vv = (node0 + r < N) ? x4[k] : make_float4(0.f, 0.f, 0.f, 0.f);
            *(float4*)&sX[r][c4 * 4] = vv;
        }
    }
    __syncthreads();
    int il = t >> 4, j = t & 15;
    float acc = 0.f;
    const float* xr = sX[il];
#pragma unroll 8
    for (int k = 0; k < F_IN; ++k) acc += xr[k] * sW[k * F_HID + j];
    int n = node0 + il;
    float v = (n < N) ? acc * dinv[n] : 0.f;
    float other = __shfl_xor(v, 1);
    if (n < N && !(j & 1)) hs1b[(size_t)n * 8 + (j >> 1)] = pk2(v, other);
}

// lane-pair row gather: 8 lanes/node = 4 pairs; pair p handles edges
// e0+p, e0+p+4, ...; within a pair, half h loads 16B (8 ch) of the row.
// Pair addresses share one 64B line -> coalescer merges.
__device__ inline void gather8(const u32* __restrict__ src, const int* __restrict__ srcs,
                               int e0, int e1, int p, int h, float* a) {
    const uint4* H = (const uint4*)src;   // 2 granules per 32B row
    int e = e0 + p;
    for (; e + 4 < e1; e += 8) {
        int i0 = srcs[e], i1 = srcs[e + 4];
        uint4 d0 = H[(size_t)i0 * 2 + h];
        uint4 d1 = H[(size_t)i1 * 2 + h];
        a[0] += bflo(d0.x) + bflo(d1.x);  a[1] += bfhi(d0.x) + bfhi(d1.x);
        a[2] += bflo(d0.y) + bflo(d1.y);  a[3] += bfhi(d0.y) + bfhi(d1.y);
        a[4] += bflo(d0.z) + bflo(d1.z);  a[5] += bfhi(d0.z) + bfhi(d1.z);
        a[6] += bflo(d0.w) + bflo(d1.w);  a[7] += bfhi(d0.w) + bfhi(d1.w);
    }
    if (e < e1) {
        uint4 d0 = H[(size_t)srcs[e] * 2 + h];
        a[0] += bflo(d0.x);  a[1] += bfhi(d0.x);
        a[2] += bflo(d0.y);  a[3] += bfhi(d0.y);
        a[4] += bflo(d0.z);  a[5] += bfhi(d0.z);
        a[6] += bflo(d0.w);  a[7] += bfhi(d0.w);
    }
}

// layer-1 agg: 32 nodes/block, 8 lanes/node; fused self/dinv/bias/relu/
// pre-scale; bf16 out.
__global__ void k_agg1(const u32* __restrict__ hs1b, const int* __restrict__ srcs,
                       const int* __restrict__ nptr, const float* __restrict__ dinv,
                       const float* __restrict__ b1, u32* __restrict__ h1b, int N) {
    int t = threadIdx.x;
    int g = t >> 3, l = t & 7;
    int p = l >> 1, h = l & 1;
    int n = blockIdx.x * 32 + g;
    if (n >= N) return;
    float a[8];
#pragma unroll
    for (int k = 0; k < 8; ++k) a[k] = 0.f;
    gather8(hs1b, srcs, nptr[n], nptr[n + 1], p, h, a);
#pragma unroll
    for (int o = 2; o <= 4; o <<= 1)      // reduce over pairs (parity-preserving)
#pragma unroll
        for (int k = 0; k < 8; ++k) a[k] += __shfl_xor(a[k], o, 64);
    if (p != 0) return;
    uint4 sd = ((const uint4*)hs1b)[(size_t)n * 2 + h];  // self, this half
    float dv = dinv[n];
    const float4* b4 = (const float4*)b1;
    float4 ba = b4[2 * h], bb = b4[2 * h + 1];
    float r0 = dv * (a[0] + bflo(sd.x)) + ba.x;
    float r1 = dv * (a[1] + bfhi(sd.x)) + ba.y;
    float r2 = dv * (a[2] + bflo(sd.y)) + ba.z;
    float r3 = dv * (a[3] + bfhi(sd.y)) + ba.w;
    float r4 = dv * (a[4] + bflo(sd.z)) + bb.x;
    float r5 = dv * (a[5] + bfhi(sd.z)) + bb.y;
    float r6 = dv * (a[6] + bflo(sd.w)) + bb.z;
    float r7 = dv * (a[7] + bfhi(sd.w)) + bb.w;
    r0 = fmaxf(r0, 0.f) * dv;  r1 = fmaxf(r1, 0.f) * dv;   // pre-scale next layer
    r2 = fmaxf(r2, 0.f) * dv;  r3 = fmaxf(r3, 0.f) * dv;
    r4 = fmaxf(r4, 0.f) * dv;  r5 = fmaxf(r5, 0.f) * dv;
    r6 = fmaxf(r6, 0.f) * dv;  r7 = fmaxf(r7, 0.f) * dv;
    ((uint4*)h1b)[(size_t)n * 2 + h] =
        make_uint4(pk2(r0, r1), pk2(r2, r3), pk2(r4, r5), pk2(r6, r7));
}

// layer-2 agg + fused 16x32 GEMM (W2) + bias + log_softmax. 32 nodes/block.
__global__ void k_agg2_final(const u32* __restrict__ h1b, const int* __restrict__ srcs,
                             const int* __restrict__ nptr, const float* __restrict__ dinv,
                             const float* __restrict__ W2, const float* __restrict__ b2,
                             float* __restrict__ out, int N) {
    __shared__ float accS[32 * 17];
    __shared__ float sW2[F_HID * F_OUT];
    __shared__ float sb2[F_OUT];
    int t = threadIdx.x;
    for (int k = t; k < F_HID * F_OUT; k += 256) sW2[k] = W2[k];
    if (t < F_OUT) sb2[t] = b2[t];
    int g = t >> 3, l = t & 7;
    int p = l >> 1, h = l & 1;
    int n = blockIdx.x * 32 + g;
    float a[8];
#pragma unroll
    for (int k = 0; k < 8; ++k) a[k] = 0.f;
    if (n < N) gather8(h1b, srcs, nptr[n], nptr[n + 1], p, h, a);
#pragma unroll
    for (int o = 2; o <= 4; o <<= 1)
#pragma unroll
        for (int k = 0; k < 8; ++k) a[k] += __shfl_xor(a[k], o, 64);
    if (n < N && p == 0) {
        uint4 sd = ((const uint4*)h1b)[(size_t)n * 2 + h];
        float dv = dinv[n];
        float* as = &accS[g * 17 + 8 * h];
        as[0] = dv * (a[0] + bflo(sd.x));
        as[1] = dv * (a[1] + bfhi(sd.x));
        as[2] = dv * (a[2] + bflo(sd.y));
        as[3] = dv * (a[3] + bfhi(sd.y));
        as[4] = dv * (a[4] + bflo(sd.z));
        as[5] = dv * (a[5] + bfhi(sd.z));
        as[6] = dv * (a[6] + bflo(sd.w));
        as[7] = dv * (a[7] + bfhi(sd.w));
    }
    __syncthreads();
    int g2 = t >> 5, j = t & 31;
    for (int r = 0; r < 4; ++r) {
        int nl = r * 8 + g2;
        int n2 = blockIdx.x * 32 + nl;
        if (n2 < N) {
            float z = sb2[j];
#pragma unroll
            for (int k = 0; k < F_HID; ++k) z += accS[nl * 17 + k] * sW2[k * F_OUT + j];
            float m = z;
            for (int o = 16; o > 0; o >>= 1) m = fmaxf(m, __shfl_xor(m, o, 32));
            float ssum = __expf(z - m);
            for (int o = 16; o > 0; o >>= 1) ssum += __shfl_xor(ssum, o, 32);
            out[(size_t)n2 * F_OUT + j] = z - m - __logf(ssum);
        }
    }
}

static inline size_t alignup(size_t v) { return (v + 255) & ~(size_t)255; }

extern "C" void kernel_launch(void* const* d_in, const int* in_sizes, int n_in,
                              void* d_out, int out_size, void* d_ws, size_t ws_size,
                              hipStream_t stream) {
    const float* x  = (const float*)d_in[0];
    const int*   ei = (const int*)d_in[1];   // [2, E] int32
    const float* W1 = (const float*)d_in[2];
    const float* b1 = (const float*)d_in[3];
    const float* W2 = (const float*)d_in[4];
    const float* b2 = (const float*)d_in[5];
    float* out = (float*)d_out;

    int N = in_sizes[0] / F_IN;
    int E = in_sizes[1] / 2;
    const int* row = ei;
    const int* col = ei + E;
    int B = (N + CN - 1) >> CSH;             // 391 coarse buckets
    int chunkB = (B + 7) >> 3;               // 49 -> padded grid 392
    int M = B * G;                            // hist size (200,192)
    int NP = (M + SCH - 1) / SCH;             // scan blocks (49, <=256)

    // ws: hist_t[M] | off[M+1] | psum[256] | nptr[B*CN+1] | dinv[N] |
    //     pairs[E] | srcs[E] | hs1b[8N] | h1b[8N]   (~35 MB)
    char* w = (char*)d_ws;
    int*   hist_t = (int*)w;   w += alignup(sizeof(int) * (size_t)M);
    int*   off    = (int*)w;   w += alignup(sizeof(int) * ((size_t)M + 1));
    int*   psum   = (int*)w;   w += alignup(sizeof(int) * 256);
    int*   nptr   = (int*)w;   w += alignup(sizeof(int) * ((size_t)B * CN + 1));
    float* dinv   = (float*)w; w += alignup(sizeof(float) * (size_t)N);
    u32*   pairs  = (u32*)w;   w += alignup(sizeof(u32) * (size_t)E);
    int*   srcs   = (int*)w;   w += alignup(sizeof(int) * (size_t)E);
    u32*   hs1b   = (u32*)w;   w += alignup(sizeof(u32) * (size_t)N * 8);
    u32*   h1b    = (u32*)w;

    k_hist<<<G, 256, 0, stream>>>(col, E, hist_t, B);
    k_scan_part<<<NP, 256, 0, stream>>>(hist_t, psum, M);
    k_scan_top<<<1, 256, 0, stream>>>(psum, NP);
    k_scan_out<<<NP, 256, 0, stream>>>(hist_t, psum, off, M);
    k_fill<<<G, 256, 0, stream>>>(row, col, E, off, pairs, B);
    k_sortfine<<<chunkB * 8, 256, 0, stream>>>(pairs, off, B, chunkB, E, nptr, dinv, srcs, N);

    k_gemm1<<<(N + 15) / 16, 256, 0, stream>>>(x, W1, dinv, hs1b, N);
    k_agg1<<<(N + 31) / 32, 256, 0, stream>>>(hs1b, srcs, nptr, dinv, b1, h1b, N);
    k_agg2_final<<<(N + 31) / 32, 256, 0, stream>>>(h1b, srcs, nptr, dinv, W2, b2, out, N);
}